// Round 1
// baseline (6303.793 us; speedup 1.0000x reference)
//
#include <hip/hip_runtime.h>
#include <cstdint>
#include <cstddef>

#define BATCH 16384

typedef float f32x4 __attribute__((ext_vector_type(4)));
typedef _Float16 f16x8 __attribute__((ext_vector_type(8)));

__device__ __forceinline__ unsigned short f2h_bits(float f) {
  _Float16 h = (_Float16)f;  // v_cvt_f16_f32, RTN
  return __builtin_bit_cast(unsigned short, h);
}

__device__ __forceinline__ void async_cp16(const void* g, void* l) {
  __builtin_amdgcn_global_load_lds(
      (const __attribute__((address_space(1))) unsigned int*)g,
      (__attribute__((address_space(3))) unsigned int*)l, 16, 0, 0);
}

// C = A[M,K] * Bw[N,K]^T + (bias + t*Wfull[:,K]), optional ReLU.
// A, Bw are fp16 (stored as ushort). Wfull is the ORIGINAL fp32 weight with
// row length K+1 (time column at index K). Output: fp16 (Ch) or fp32 (Cf).
template <int BM, int BN, int WROWS, int WCOLS, int RT, int CT, bool RELU, bool OUTF16>
__launch_bounds__(256)
__global__ void gemm_f16(const unsigned short* __restrict__ A,
                         const unsigned short* __restrict__ Bw,
                         const float* __restrict__ Wfull,
                         const float* __restrict__ bias,
                         float tval, int K, int N,
                         unsigned short* __restrict__ Ch,
                         float* __restrict__ Cf) {
  constexpr int BK = 32;
  __shared__ __align__(16) unsigned short smA[BM * BK];
  __shared__ __align__(16) unsigned short smB[BN * BK];

  const int tid = threadIdx.x;
  const int wave = tid >> 6;
  const int lane = tid & 63;
  const int quad = lane >> 4;
  const int r16 = lane & 15;

  const int rowA0 = blockIdx.x * BM;
  const int rowB0 = blockIdx.y * BN;

  const int waveM = wave / WCOLS;
  const int waveN = wave % WCOLS;

  f32x4 acc[RT][CT];
  const f32x4 zero = {0.f, 0.f, 0.f, 0.f};
#pragma unroll
  for (int i = 0; i < RT; ++i)
#pragma unroll
    for (int j = 0; j < CT; ++j) acc[i][j] = zero;

  for (int k0 = 0; k0 < K; k0 += BK) {
    // ---- stage A tile [BM][BK] (row-major, no pad: required by global_load_lds) ----
#pragma unroll
    for (int i = 0; i < BM / 64; ++i) {
      const int chunk = i * 256 + tid;           // 16B chunk id
      const int ra = chunk >> 2;                 // row in tile
      const int ca = chunk & 3;                  // 8-elem col chunk
      const unsigned short* g = A + (size_t)(rowA0 + ra) * K + (k0 + ca * 8);
      char* l = ((char*)smA) + (size_t)(i * 256 + (wave << 6)) * 16;  // wave-uniform base
      async_cp16(g, l);
    }
    // ---- stage B tile [BN][BK] (B^T layout: rows are output cols) ----
#pragma unroll
    for (int i = 0; i < BN / 64; ++i) {
      const int chunk = i * 256 + tid;
      const int rb = chunk >> 2;
      const int cb = chunk & 3;
      const unsigned short* g = Bw + (size_t)(rowB0 + rb) * K + (k0 + cb * 8);
      char* l = ((char*)smB) + (size_t)(i * 256 + (wave << 6)) * 16;
      async_cp16(g, l);
    }
    __syncthreads();  // compiler emits vmcnt(0) drain for the async loads

    // ---- fragments: lane holds row (lane&15), k = (lane>>4)*8 .. +7 ----
    f16x8 af[RT], bfr[CT];
#pragma unroll
    for (int mt = 0; mt < RT; ++mt) {
      const int row = (waveM * RT + mt) * 16 + r16;
      af[mt] = *(const f16x8*)(smA + row * BK + quad * 8);
    }
#pragma unroll
    for (int nt = 0; nt < CT; ++nt) {
      const int row = (waveN * CT + nt) * 16 + r16;
      bfr[nt] = *(const f16x8*)(smB + row * BK + quad * 8);
    }
#pragma unroll
    for (int mt = 0; mt < RT; ++mt)
#pragma unroll
      for (int nt = 0; nt < CT; ++nt)
        acc[mt][nt] = __builtin_amdgcn_mfma_f32_16x16x32_f16(af[mt], bfr[nt], acc[mt][nt], 0, 0, 0);
    __syncthreads();
  }

  // ---- effective bias = b[col] + t * Wfull[col][K]  (time-column fold) ----
  float* biasLds = (float*)smA;  // reuse A staging LDS (all reads drained at last barrier)
  if (tid < BN) {
    const int col = rowB0 + tid;
    biasLds[tid] = bias[col] + tval * Wfull[(size_t)col * (K + 1) + K];
  }
  __syncthreads();

  // ---- epilogue: C/D layout col=lane&15, row=(lane>>4)*4+r ----
#pragma unroll
  for (int mt = 0; mt < RT; ++mt) {
    const int grow0 = rowA0 + (waveM * RT + mt) * 16 + quad * 4;
#pragma unroll
    for (int nt = 0; nt < CT; ++nt) {
      const int lcol = (waveN * CT + nt) * 16 + r16;
      const int gcol = rowB0 + lcol;
      const float bi = biasLds[lcol];
#pragma unroll
      for (int r = 0; r < 4; ++r) {
        float v = acc[mt][nt][r] + bi;
        if (RELU) v = fmaxf(v, 0.0f);
        const size_t off = (size_t)(grow0 + r) * N + gcol;
        if (OUTF16) Ch[off] = f2h_bits(v);
        else Cf[off] = v;
      }
    }
  }
}

// fp32 W (N x (K+1), time col dropped) -> fp16 Wh (N x K)
__global__ void conv_w(const float* __restrict__ W, unsigned short* __restrict__ Wh,
                       int N, int K) {
  const int idx = blockIdx.x * 256 + threadIdx.x;
  if (idx < N * K) {
    const int n = idx / K;
    const int k = idx - n * K;
    Wh[idx] = f2h_bits(W[(size_t)n * (K + 1) + k]);
  }
}

// y0 = concat(x, aug); also fp16 copy for first GEMM
__global__ void init_y(const float* __restrict__ x, const float* __restrict__ aug,
                       float* __restrict__ y, unsigned short* __restrict__ yh) {
  const int idx = blockIdx.x * 256 + threadIdx.x;  // BATCH*64
  const int i = idx >> 6;
  const int j = idx & 63;
  const float v = (j < 32) ? x[i * 32 + j] : aug[i * 32 + (j - 32)];
  y[idx] = v;
  yh[idx] = f2h_bits(v);
}

// RK4 bookkeeping after each odefunc eval.
// mode 0: ksum = k;      yh = h(y + 0.5dt*k)
// mode 1: ksum += 2k;    yh = h(y + 0.5dt*k)
// mode 2: ksum += 2k;    yh = h(y + dt*k)
// mode 3: y += dt/6*(ksum + k); yh = h(y); optionally write out[:, :32]
__global__ void combine(float* __restrict__ y, const float* __restrict__ kcur,
                        float* __restrict__ ksum, unsigned short* __restrict__ yh,
                        float* __restrict__ outp, int mode, float dt) {
  const int idx = blockIdx.x * 256 + threadIdx.x;
  const float k = kcur[idx];
  const float yv = y[idx];
  if (mode == 0) {
    ksum[idx] = k;
    yh[idx] = f2h_bits(yv + 0.5f * dt * k);
  } else if (mode == 1) {
    ksum[idx] += 2.f * k;
    yh[idx] = f2h_bits(yv + 0.5f * dt * k);
  } else if (mode == 2) {
    ksum[idx] += 2.f * k;
    yh[idx] = f2h_bits(yv + dt * k);
  } else {
    const float yn = yv + (dt / 6.f) * (ksum[idx] + k);
    y[idx] = yn;
    yh[idx] = f2h_bits(yn);
    if (outp) {
      const int i = idx >> 6;
      const int j = idx & 63;
      if (j < 32) outp[i * 32 + j] = yn;
    }
  }
}

extern "C" void kernel_launch(void* const* d_in, const int* in_sizes, int n_in,
                              void* d_out, int out_size, void* d_ws, size_t ws_size,
                              hipStream_t stream) {
  const float* x = (const float*)d_in[0];
  const float* aug = (const float*)d_in[1];
  const float* W[5];
  const float* b[5];
  for (int i = 0; i < 5; ++i) {
    W[i] = (const float*)d_in[2 + 2 * i];
    b[i] = (const float*)d_in[3 + 2 * i];
  }

  char* ws = (char*)d_ws;
  auto alloc = [&](size_t bytes) -> char* {
    char* p = ws;
    ws += (bytes + 255) & ~(size_t)255;
    return p;
  };
  float* y = (float*)alloc((size_t)BATCH * 64 * 4);
  unsigned short* yh = (unsigned short*)alloc((size_t)BATCH * 64 * 2);
  unsigned short* h1 = (unsigned short*)alloc((size_t)BATCH * 1024 * 2);
  unsigned short* h2 = (unsigned short*)alloc((size_t)BATCH * 1024 * 2);
  float* kcur = (float*)alloc((size_t)BATCH * 64 * 4);
  float* ksum = (float*)alloc((size_t)BATCH * 64 * 4);
  const int Kdim[5] = {64, 1024, 1024, 1024, 1024};
  const int Ndim[5] = {1024, 1024, 1024, 1024, 64};
  unsigned short* Wh[5];
  for (int i = 0; i < 5; ++i)
    Wh[i] = (unsigned short*)alloc((size_t)Ndim[i] * Kdim[i] * 2);

  for (int i = 0; i < 5; ++i) {
    const int total = Ndim[i] * Kdim[i];
    conv_w<<<(total + 255) / 256, 256, 0, stream>>>(W[i], Wh[i], Ndim[i], Kdim[i]);
  }
  init_y<<<BATCH * 64 / 256, 256, 0, stream>>>(x, aug, y, yh);

  const float dt = 0.125f;
  auto eval = [&](float t) {
    // layer 0: [B,64] x [64,1024]^T -> h1 (fp16, relu)
    gemm_f16<128, 128, 2, 2, 4, 4, true, true>
        <<<dim3(BATCH / 128, 1024 / 128), 256, 0, stream>>>(
            yh, Wh[0], W[0], b[0], t, 64, 1024, h1, nullptr);
    unsigned short* src = h1;
    unsigned short* dst = h2;
    for (int L = 1; L <= 3; ++L) {
      gemm_f16<128, 128, 2, 2, 4, 4, true, true>
          <<<dim3(BATCH / 128, 1024 / 128), 256, 0, stream>>>(
              src, Wh[L], W[L], b[L], t, 1024, 1024, dst, nullptr);
      unsigned short* tmp = src; src = dst; dst = tmp;
    }
    // layer 4: [B,1024] x [1024,64]^T -> kcur (fp32, no relu)
    gemm_f16<64, 64, 4, 1, 1, 4, false, false>
        <<<dim3(BATCH / 64, 1), 256, 0, stream>>>(
            src, Wh[4], W[4], b[4], t, 1024, 64, nullptr, kcur);
  };

  float* outp = (float*)d_out;
  for (int s = 0; s < 8; ++s) {
    const float t0 = s * dt;
    eval(t0);
    combine<<<BATCH * 64 / 256, 256, 0, stream>>>(y, kcur, ksum, yh, nullptr, 0, dt);
    eval(t0 + 0.5f * dt);
    combine<<<BATCH * 64 / 256, 256, 0, stream>>>(y, kcur, ksum, yh, nullptr, 1, dt);
    eval(t0 + 0.5f * dt);
    combine<<<BATCH * 64 / 256, 256, 0, stream>>>(y, kcur, ksum, yh, nullptr, 2, dt);
    eval(t0 + dt);
    combine<<<BATCH * 64 / 256, 256, 0, stream>>>(y, kcur, ksum, yh,
                                                  (s == 7) ? outp : nullptr, 3, dt);
  }
}

// Round 2
// 5244.497 us; speedup vs baseline: 1.2020x; 1.2020x over previous
//
#include <hip/hip_runtime.h>
#include <cstdint>
#include <cstddef>

#define BATCH 16384

typedef float f32x4 __attribute__((ext_vector_type(4)));
typedef _Float16 f16x8 __attribute__((ext_vector_type(8)));

__device__ __forceinline__ unsigned short f2h_bits(float f) {
  _Float16 h = (_Float16)f;
  return __builtin_bit_cast(unsigned short, h);
}

__device__ __forceinline__ void async_cp16(const void* g, void* l) {
  __builtin_amdgcn_global_load_lds(
      (const __attribute__((address_space(1))) unsigned int*)g,
      (__attribute__((address_space(3))) unsigned int*)l, 16, 0, 0);
}

// ---------------------------------------------------------------------------
// Hidden-layer GEMM: C = relu(A[M,K] * Bw[N,K]^T + (bias + t*Wfull[:,K]))
// A, Bw fp16 (ushort). BK=64, XOR-swizzled LDS: 16B chunk (row, c) lives at
// LDS chunk position row*8 + (c ^ (row&7)). Staging iterates LDS positions
// linearly (global_load_lds requires lane-linear LDS dest) and permutes the
// GLOBAL chunk index instead. Fragment ds_read_b128 then covers all 8 bank
// groups across a quad's 16 lanes -> conflict-free at 128B row stride.
// ---------------------------------------------------------------------------
template <int BM, int BN, int WCOLS, int RT, int CT, int K, int N, bool RELU>
__launch_bounds__(256)
__global__ void gemm_h(const unsigned short* __restrict__ A,
                       const unsigned short* __restrict__ Bw,
                       const float* __restrict__ Wfull,
                       const float* __restrict__ bias,
                       float tval,
                       unsigned short* __restrict__ Ch) {
  constexpr int BK = 64;
  __shared__ __align__(16) unsigned short smA[BM * BK];
  __shared__ __align__(16) unsigned short smB[BN * BK];

  const int tid = threadIdx.x;
  const int wave = tid >> 6;
  const int lane = tid & 63;
  const int quad = lane >> 4;
  const int r16 = lane & 15;

  const int rowA0 = blockIdx.x * BM;
  const int rowB0 = blockIdx.y * BN;

  const int waveM = wave / WCOLS;
  const int waveN = wave % WCOLS;

  f32x4 acc[RT][CT];
  const f32x4 zero = {0.f, 0.f, 0.f, 0.f};
#pragma unroll
  for (int i = 0; i < RT; ++i)
#pragma unroll
    for (int j = 0; j < CT; ++j) acc[i][j] = zero;

  for (int k0 = 0; k0 < K; k0 += BK) {
    // ---- stage A tile [BM][BK]: BM*8 16B chunks, swizzled ----
#pragma unroll
    for (int i = 0; i < BM * 8 / 256; ++i) {
      const int s = i * 256 + tid;        // LDS chunk position (lane-linear)
      const int row = s >> 3;
      const int cp = s & 7;
      const int c = cp ^ (row & 7);       // global 8-elem chunk index
      const unsigned short* g = A + (size_t)(rowA0 + row) * K + (k0 + c * 8);
      char* l = ((char*)smA) + (size_t)(i * 256 + (wave << 6)) * 16;
      async_cp16(g, l);
    }
#pragma unroll
    for (int i = 0; i < BN * 8 / 256; ++i) {
      const int s = i * 256 + tid;
      const int row = s >> 3;
      const int cp = s & 7;
      const int c = cp ^ (row & 7);
      const unsigned short* g = Bw + (size_t)(rowB0 + row) * K + (k0 + c * 8);
      char* l = ((char*)smB) + (size_t)(i * 256 + (wave << 6)) * 16;
      async_cp16(g, l);
    }
    __syncthreads();

    // ---- 2 k-halves of 32 per stage; frag chunk c = h*4+quad, swizzled ----
#pragma unroll
    for (int h = 0; h < 2; ++h) {
      f16x8 af[RT], bfr[CT];
#pragma unroll
      for (int mt = 0; mt < RT; ++mt) {
        const int row = (waveM * RT + mt) * 16 + r16;
        const int cp = (h * 4 + quad) ^ (row & 7);
        af[mt] = *(const f16x8*)(smA + row * BK + cp * 8);
      }
#pragma unroll
      for (int nt = 0; nt < CT; ++nt) {
        const int row = (waveN * CT + nt) * 16 + r16;
        const int cp = (h * 4 + quad) ^ (row & 7);
        bfr[nt] = *(const f16x8*)(smB + row * BK + cp * 8);
      }
#pragma unroll
      for (int mt = 0; mt < RT; ++mt)
#pragma unroll
        for (int nt = 0; nt < CT; ++nt)
          acc[mt][nt] =
              __builtin_amdgcn_mfma_f32_16x16x32_f16(af[mt], bfr[nt], acc[mt][nt], 0, 0, 0);
    }
    __syncthreads();
  }

  // ---- effective bias = b[col] + t * Wfull[col][K] (time-column fold) ----
  float* biasLds = (float*)smA;
  if (tid < BN) {
    const int col = rowB0 + tid;
    biasLds[tid] = bias[col] + tval * Wfull[(size_t)col * (K + 1) + K];
  }
  __syncthreads();

  // ---- epilogue: C/D layout col=lane&15, row=(lane>>4)*4+r ----
#pragma unroll
  for (int mt = 0; mt < RT; ++mt) {
    const int grow0 = rowA0 + (waveM * RT + mt) * 16 + quad * 4;
#pragma unroll
    for (int nt = 0; nt < CT; ++nt) {
      const int lcol = (waveN * CT + nt) * 16 + r16;
      const int gcol = rowB0 + lcol;
      const float bi = biasLds[lcol];
#pragma unroll
      for (int r = 0; r < 4; ++r) {
        float v = acc[mt][nt][r] + bi;
        if (RELU) v = fmaxf(v, 0.0f);
        Ch[(size_t)(grow0 + r) * N + gcol] = f2h_bits(v);
      }
    }
  }
}

// ---------------------------------------------------------------------------
// Last layer fused with RK4 combine. Tile 32x64 (BN=64=full width -> each
// block owns complete k rows, so the elementwise RK4 update fuses into the
// epilogue). K=1024, BK=64, same swizzle. mode: 0..3 (see below).
// ---------------------------------------------------------------------------
__launch_bounds__(256)
__global__ void gemm_l4(const unsigned short* __restrict__ A,
                        const unsigned short* __restrict__ Bw,
                        const float* __restrict__ Wfull,
                        const float* __restrict__ bias,
                        float tval,
                        float* __restrict__ y, float* __restrict__ ksum,
                        unsigned short* __restrict__ yh,
                        float* __restrict__ outp, int mode, float dt) {
  constexpr int K = 1024, BK = 64, BM = 32, BN = 64;
  __shared__ __align__(16) unsigned short smA[BM * BK];
  __shared__ __align__(16) unsigned short smB[BN * BK];

  const int tid = threadIdx.x;
  const int wave = tid >> 6;
  const int lane = tid & 63;
  const int quad = lane >> 4;
  const int r16 = lane & 15;

  const int rowA0 = blockIdx.x * BM;
  const int waveM = wave >> 1;   // 2 wave-rows
  const int waveN = wave & 1;    // 2 wave-cols (of 32)

  f32x4 acc[2];
  const f32x4 zero = {0.f, 0.f, 0.f, 0.f};
  acc[0] = zero; acc[1] = zero;

  for (int k0 = 0; k0 < K; k0 += BK) {
    {  // A: 32*8 = 256 chunks
      const int s = tid;
      const int row = s >> 3;
      const int cp = s & 7;
      const int c = cp ^ (row & 7);
      const unsigned short* g = A + (size_t)(rowA0 + row) * K + (k0 + c * 8);
      char* l = ((char*)smA) + (size_t)(wave << 6) * 16;
      async_cp16(g, l);
    }
#pragma unroll
    for (int i = 0; i < 2; ++i) {  // B: 64*8 = 512 chunks
      const int s = i * 256 + tid;
      const int row = s >> 3;
      const int cp = s & 7;
      const int c = cp ^ (row & 7);
      const unsigned short* g = Bw + (size_t)row * K + (k0 + c * 8);
      char* l = ((char*)smB) + (size_t)(i * 256 + (wave << 6)) * 16;
      async_cp16(g, l);
    }
    __syncthreads();

#pragma unroll
    for (int h = 0; h < 2; ++h) {
      f16x8 af, bfr[2];
      {
        const int row = waveM * 16 + r16;
        const int cp = (h * 4 + quad) ^ (row & 7);
        af = *(const f16x8*)(smA + row * BK + cp * 8);
      }
#pragma unroll
      for (int nt = 0; nt < 2; ++nt) {
        const int row = (waveN * 2 + nt) * 16 + r16;
        const int cp = (h * 4 + quad) ^ (row & 7);
        bfr[nt] = *(const f16x8*)(smB + row * BK + cp * 8);
      }
#pragma unroll
      for (int nt = 0; nt < 2; ++nt)
        acc[nt] = __builtin_amdgcn_mfma_f32_16x16x32_f16(af, bfr[nt], acc[nt], 0, 0, 0);
    }
    __syncthreads();
  }

  float* biasLds = (float*)smA;
  if (tid < BN) {
    biasLds[tid] = bias[tid] + tval * Wfull[(size_t)tid * (K + 1) + K];
  }
  __syncthreads();

  // epilogue + fused RK4 combine
  const int grow0 = rowA0 + waveM * 16 + quad * 4;
#pragma unroll
  for (int nt = 0; nt < 2; ++nt) {
    const int col = waveN * 32 + nt * 16 + r16;
    const float bi = biasLds[col];
#pragma unroll
    for (int r = 0; r < 4; ++r) {
      const float k = acc[nt][r] + bi;   // odefunc output element
      const int row = grow0 + r;
      const int idx = row * 64 + col;
      if (mode == 0) {
        ksum[idx] = k;
        yh[idx] = f2h_bits(y[idx] + 0.5f * dt * k);
      } else if (mode == 1) {
        ksum[idx] += 2.f * k;
        yh[idx] = f2h_bits(y[idx] + 0.5f * dt * k);
      } else if (mode == 2) {
        ksum[idx] += 2.f * k;
        yh[idx] = f2h_bits(y[idx] + dt * k);
      } else {
        const float yn = y[idx] + (dt / 6.f) * (ksum[idx] + k);
        y[idx] = yn;
        yh[idx] = f2h_bits(yn);
        if (outp && col < 32) outp[row * 32 + col] = yn;
      }
    }
  }
}

// fp32 W (N x (K+1), time col dropped) -> fp16 Wh (N x K)
__global__ void conv_w(const float* __restrict__ W, unsigned short* __restrict__ Wh,
                       int N, int K) {
  const int idx = blockIdx.x * 256 + threadIdx.x;
  if (idx < N * K) {
    const int n = idx / K;
    const int k = idx - n * K;
    Wh[idx] = f2h_bits(W[(size_t)n * (K + 1) + k]);
  }
}

// y0 = concat(x, aug); also fp16 copy for first GEMM
__global__ void init_y(const float* __restrict__ x, const float* __restrict__ aug,
                       float* __restrict__ y, unsigned short* __restrict__ yh) {
  const int idx = blockIdx.x * 256 + threadIdx.x;  // BATCH*64
  const int i = idx >> 6;
  const int j = idx & 63;
  const float v = (j < 32) ? x[i * 32 + j] : aug[i * 32 + (j - 32)];
  y[idx] = v;
  yh[idx] = f2h_bits(v);
}

extern "C" void kernel_launch(void* const* d_in, const int* in_sizes, int n_in,
                              void* d_out, int out_size, void* d_ws, size_t ws_size,
                              hipStream_t stream) {
  const float* x = (const float*)d_in[0];
  const float* aug = (const float*)d_in[1];
  const float* W[5];
  const float* b[5];
  for (int i = 0; i < 5; ++i) {
    W[i] = (const float*)d_in[2 + 2 * i];
    b[i] = (const float*)d_in[3 + 2 * i];
  }

  char* ws = (char*)d_ws;
  auto alloc = [&](size_t bytes) -> char* {
    char* p = ws;
    ws += (bytes + 255) & ~(size_t)255;
    return p;
  };
  float* y = (float*)alloc((size_t)BATCH * 64 * 4);
  unsigned short* yh = (unsigned short*)alloc((size_t)BATCH * 64 * 2);
  unsigned short* h1 = (unsigned short*)alloc((size_t)BATCH * 1024 * 2);
  unsigned short* h2 = (unsigned short*)alloc((size_t)BATCH * 1024 * 2);
  float* ksum = (float*)alloc((size_t)BATCH * 64 * 4);
  const int Kdim[5] = {64, 1024, 1024, 1024, 1024};
  const int Ndim[5] = {1024, 1024, 1024, 1024, 64};
  unsigned short* Wh[5];
  for (int i = 0; i < 5; ++i)
    Wh[i] = (unsigned short*)alloc((size_t)Ndim[i] * Kdim[i] * 2);

  for (int i = 0; i < 5; ++i) {
    const int total = Ndim[i] * Kdim[i];
    conv_w<<<(total + 255) / 256, 256, 0, stream>>>(W[i], Wh[i], Ndim[i], Kdim[i]);
  }
  init_y<<<BATCH * 64 / 256, 256, 0, stream>>>(x, aug, y, yh);

  const float dt = 0.125f;
  float* outp = (float*)d_out;

  auto eval = [&](float t, int mode, float* op) {
    // layer 0: [B,64] x [64,1024]^T -> h1 (single BK=64 stage)
    gemm_h<128, 128, 2, 4, 4, 64, 1024, true>
        <<<dim3(BATCH / 128, 1024 / 128), 256, 0, stream>>>(
            yh, Wh[0], W[0], b[0], t, h1);
    unsigned short* src = h1;
    unsigned short* dst = h2;
    for (int L = 1; L <= 3; ++L) {
      gemm_h<128, 128, 2, 4, 4, 1024, 1024, true>
          <<<dim3(BATCH / 128, 1024 / 128), 256, 0, stream>>>(
              src, Wh[L], W[L], b[L], t, dst);
      unsigned short* tmp = src; src = dst; dst = tmp;
    }
    // layer 4 + fused RK4 combine
    gemm_l4<<<dim3(BATCH / 32, 1), 256, 0, stream>>>(
        src, Wh[4], W[4], b[4], t, y, ksum, yh, op, mode, dt);
  };

  for (int s = 0; s < 8; ++s) {
    const float t0 = s * dt;
    eval(t0, 0, nullptr);
    eval(t0 + 0.5f * dt, 1, nullptr);
    eval(t0 + 0.5f * dt, 2, nullptr);
    eval(t0 + dt, 3, (s == 7) ? outp : nullptr);
  }
}

// Round 3
// 4945.045 us; speedup vs baseline: 1.2748x; 1.0606x over previous
//
#include <hip/hip_runtime.h>
#include <cstdint>
#include <cstddef>

#define BATCH 16384

typedef float f32x4 __attribute__((ext_vector_type(4)));
typedef _Float16 f16x8 __attribute__((ext_vector_type(8)));

__device__ __forceinline__ unsigned short f2h_bits(float f) {
  _Float16 h = (_Float16)f;
  return __builtin_bit_cast(unsigned short, h);
}

__device__ __forceinline__ void async_cp16(const void* g, void* l) {
  __builtin_amdgcn_global_load_lds(
      (const __attribute__((address_space(1))) unsigned int*)g,
      (__attribute__((address_space(3))) unsigned int*)l, 16, 0, 0);
}

// ---------------------------------------------------------------------------
// Hidden-layer GEMM, double-buffered: C = relu(A*Bw^T + (bias + t*W[:,K])).
// BK=32 (4 x 16B chunks per row). XOR swizzle cp = c ^ ((row>>1)&3): over 8
// consecutive rows the 4 quads cover all 8 bank granules -> 2-way conflict
// (free per m136). Loads for iter k+1 are issued BEFORE iter k's compute, so
// the vmcnt(0) drain at the next __syncthreads has had a full compute phase
// to complete -> load latency hidden.
// ---------------------------------------------------------------------------
template <int BM, int BN, int WCOLS, int RT, int CT, int K, int N, bool RELU>
__launch_bounds__(256, 4)
__global__ void gemm_h(const unsigned short* __restrict__ A,
                       const unsigned short* __restrict__ Bw,
                       const float* __restrict__ Wfull,
                       const float* __restrict__ bias,
                       float tval,
                       unsigned short* __restrict__ Ch) {
  constexpr int BK = 32;
  constexpr int NI = K / BK;
  __shared__ __align__(16) unsigned short smA[2][BM * BK];
  __shared__ __align__(16) unsigned short smB[2][BN * BK];
  __shared__ float biasLds[BN];

  const int tid = threadIdx.x;
  const int wave = tid >> 6;
  const int lane = tid & 63;
  const int quad = lane >> 4;
  const int r16 = lane & 15;

  const int rowA0 = blockIdx.x * BM;
  const int rowB0 = blockIdx.y * BN;
  const int waveM = wave / WCOLS;
  const int waveN = wave % WCOLS;

  // effective bias = b[col] + t * W[col][K] (time-column fold), before K-loop
  if (tid < BN) {
    const int col = rowB0 + tid;
    biasLds[tid] = bias[col] + tval * Wfull[(size_t)col * (K + 1) + K];
  }

  auto stage = [&](int k0, int buf) {
#pragma unroll
    for (int i = 0; i < BM * 4 / 256; ++i) {
      const int s = i * 256 + tid;                // LDS 16B-chunk position
      const int row = s >> 2;
      const int c = (s & 3) ^ ((row >> 1) & 3);   // global chunk (swizzled)
      const unsigned short* g = A + (size_t)(rowA0 + row) * K + (k0 + c * 8);
      char* l = ((char*)smA[buf]) + (size_t)(i * 256 + (wave << 6)) * 16;
      async_cp16(g, l);
    }
#pragma unroll
    for (int i = 0; i < BN * 4 / 256; ++i) {
      const int s = i * 256 + tid;
      const int row = s >> 2;
      const int c = (s & 3) ^ ((row >> 1) & 3);
      const unsigned short* g = Bw + (size_t)(rowB0 + row) * K + (k0 + c * 8);
      char* l = ((char*)smB[buf]) + (size_t)(i * 256 + (wave << 6)) * 16;
      async_cp16(g, l);
    }
  };

  f32x4 acc[RT][CT];
  const f32x4 zero = {0.f, 0.f, 0.f, 0.f};
#pragma unroll
  for (int i = 0; i < RT; ++i)
#pragma unroll
    for (int j = 0; j < CT; ++j) acc[i][j] = zero;

  stage(0, 0);  // prefetch iter 0

#pragma unroll 2
  for (int kk = 0; kk < NI; ++kk) {
    __syncthreads();  // drains vmcnt(0): buf[kk&1] is ready
    if (kk + 1 < NI) stage((kk + 1) * BK, (kk + 1) & 1);  // prefetch next

    const unsigned short* sA = smA[kk & 1];
    const unsigned short* sB = smB[kk & 1];
    f16x8 af[RT], bfr[CT];
#pragma unroll
    for (int mt = 0; mt < RT; ++mt) {
      const int row = (waveM * RT + mt) * 16 + r16;
      const int cp = quad ^ ((row >> 1) & 3);
      af[mt] = *(const f16x8*)(sA + row * BK + cp * 8);
    }
#pragma unroll
    for (int nt = 0; nt < CT; ++nt) {
      const int row = (waveN * CT + nt) * 16 + r16;
      const int cp = quad ^ ((row >> 1) & 3);
      bfr[nt] = *(const f16x8*)(sB + row * BK + cp * 8);
    }
#pragma unroll
    for (int mt = 0; mt < RT; ++mt)
#pragma unroll
      for (int nt = 0; nt < CT; ++nt)
        acc[mt][nt] =
            __builtin_amdgcn_mfma_f32_16x16x32_f16(af[mt], bfr[nt], acc[mt][nt], 0, 0, 0);
  }

  // epilogue: C/D layout col=lane&15, row=(lane>>4)*4+r
#pragma unroll
  for (int mt = 0; mt < RT; ++mt) {
    const int grow0 = rowA0 + (waveM * RT + mt) * 16 + quad * 4;
#pragma unroll
    for (int nt = 0; nt < CT; ++nt) {
      const int lcol = (waveN * CT + nt) * 16 + r16;
      const int gcol = rowB0 + lcol;
      const float bi = biasLds[lcol];
#pragma unroll
      for (int r = 0; r < 4; ++r) {
        float v = acc[mt][nt][r] + bi;
        if (RELU) v = fmaxf(v, 0.0f);
        Ch[(size_t)(grow0 + r) * N + gcol] = f2h_bits(v);
      }
    }
  }
}

// ---------------------------------------------------------------------------
// Last layer fused with RK4 combine, same dbuf structure. BM=32, BN=64 (full
// output width -> block owns complete rows of k, RK4 update in epilogue).
// ---------------------------------------------------------------------------
__launch_bounds__(256, 4)
__global__ void gemm_l4(const unsigned short* __restrict__ A,
                        const unsigned short* __restrict__ Bw,
                        const float* __restrict__ Wfull,
                        const float* __restrict__ bias,
                        float tval,
                        float* __restrict__ y, float* __restrict__ ksum,
                        unsigned short* __restrict__ yh,
                        float* __restrict__ outp, int mode, float dt) {
  constexpr int K = 1024, BK = 32, BM = 32, BN = 64, NI = K / BK;
  __shared__ __align__(16) unsigned short smA[2][BM * BK];
  __shared__ __align__(16) unsigned short smB[2][BN * BK];
  __shared__ float biasLds[BN];

  const int tid = threadIdx.x;
  const int wave = tid >> 6;
  const int lane = tid & 63;
  const int quad = lane >> 4;
  const int r16 = lane & 15;

  const int rowA0 = blockIdx.x * BM;
  const int waveM = wave >> 1;
  const int waveN = wave & 1;

  if (tid < BN) {
    biasLds[tid] = bias[tid] + tval * Wfull[(size_t)tid * (K + 1) + K];
  }

  auto stage = [&](int k0, int buf) {
    if (tid < BM * 4) {  // A: 128 chunks (waves 0-1)
      const int s = tid;
      const int row = s >> 2;
      const int c = (s & 3) ^ ((row >> 1) & 3);
      const unsigned short* g = A + (size_t)(rowA0 + row) * K + (k0 + c * 8);
      char* l = ((char*)smA[buf]) + (size_t)(wave << 6) * 16;
      async_cp16(g, l);
    }
    {  // B: 256 chunks
      const int s = tid;
      const int row = s >> 2;
      const int c = (s & 3) ^ ((row >> 1) & 3);
      const unsigned short* g = Bw + (size_t)row * K + (k0 + c * 8);
      char* l = ((char*)smB[buf]) + (size_t)(wave << 6) * 16;
      async_cp16(g, l);
    }
  };

  f32x4 acc[2];
  const f32x4 zero = {0.f, 0.f, 0.f, 0.f};
  acc[0] = zero; acc[1] = zero;

  stage(0, 0);

#pragma unroll 2
  for (int kk = 0; kk < NI; ++kk) {
    __syncthreads();
    if (kk + 1 < NI) stage((kk + 1) * BK, (kk + 1) & 1);

    const unsigned short* sA = smA[kk & 1];
    const unsigned short* sB = smB[kk & 1];
    f16x8 af, bfr[2];
    {
      const int row = waveM * 16 + r16;
      const int cp = quad ^ ((row >> 1) & 3);
      af = *(const f16x8*)(sA + row * BK + cp * 8);
    }
#pragma unroll
    for (int nt = 0; nt < 2; ++nt) {
      const int row = (waveN * 2 + nt) * 16 + r16;
      const int cp = quad ^ ((row >> 1) & 3);
      bfr[nt] = *(const f16x8*)(sB + row * BK + cp * 8);
    }
#pragma unroll
    for (int nt = 0; nt < 2; ++nt)
      acc[nt] = __builtin_amdgcn_mfma_f32_16x16x32_f16(af, bfr[nt], acc[nt], 0, 0, 0);
  }

  // epilogue + fused RK4 combine
  const int grow0 = rowA0 + waveM * 16 + quad * 4;
#pragma unroll
  for (int nt = 0; nt < 2; ++nt) {
    const int col = waveN * 32 + nt * 16 + r16;
    const float bi = biasLds[col];
#pragma unroll
    for (int r = 0; r < 4; ++r) {
      const float k = acc[nt][r] + bi;
      const int row = grow0 + r;
      const int idx = row * 64 + col;
      if (mode == 0) {
        ksum[idx] = k;
        yh[idx] = f2h_bits(y[idx] + 0.5f * dt * k);
      } else if (mode == 1) {
        ksum[idx] += 2.f * k;
        yh[idx] = f2h_bits(y[idx] + 0.5f * dt * k);
      } else if (mode == 2) {
        ksum[idx] += 2.f * k;
        yh[idx] = f2h_bits(y[idx] + dt * k);
      } else {
        const float yn = y[idx] + (dt / 6.f) * (ksum[idx] + k);
        y[idx] = yn;
        yh[idx] = f2h_bits(yn);
        if (outp && col < 32) outp[row * 32 + col] = yn;
      }
    }
  }
}

// fp32 W (N x (K+1), time col dropped) -> fp16 Wh (N x K)
__global__ void conv_w(const float* __restrict__ W, unsigned short* __restrict__ Wh,
                       int N, int K) {
  const int idx = blockIdx.x * 256 + threadIdx.x;
  if (idx < N * K) {
    const int n = idx / K;
    const int k = idx - n * K;
    Wh[idx] = f2h_bits(W[(size_t)n * (K + 1) + k]);
  }
}

// y0 = concat(x, aug); also fp16 copy for first GEMM
__global__ void init_y(const float* __restrict__ x, const float* __restrict__ aug,
                       float* __restrict__ y, unsigned short* __restrict__ yh) {
  const int idx = blockIdx.x * 256 + threadIdx.x;  // BATCH*64
  const int i = idx >> 6;
  const int j = idx & 63;
  const float v = (j < 32) ? x[i * 32 + j] : aug[i * 32 + (j - 32)];
  y[idx] = v;
  yh[idx] = f2h_bits(v);
}

extern "C" void kernel_launch(void* const* d_in, const int* in_sizes, int n_in,
                              void* d_out, int out_size, void* d_ws, size_t ws_size,
                              hipStream_t stream) {
  const float* x = (const float*)d_in[0];
  const float* aug = (const float*)d_in[1];
  const float* W[5];
  const float* b[5];
  for (int i = 0; i < 5; ++i) {
    W[i] = (const float*)d_in[2 + 2 * i];
    b[i] = (const float*)d_in[3 + 2 * i];
  }

  char* ws = (char*)d_ws;
  auto alloc = [&](size_t bytes) -> char* {
    char* p = ws;
    ws += (bytes + 255) & ~(size_t)255;
    return p;
  };
  float* y = (float*)alloc((size_t)BATCH * 64 * 4);
  unsigned short* yh = (unsigned short*)alloc((size_t)BATCH * 64 * 2);
  unsigned short* h1 = (unsigned short*)alloc((size_t)BATCH * 1024 * 2);
  unsigned short* h2 = (unsigned short*)alloc((size_t)BATCH * 1024 * 2);
  float* ksum = (float*)alloc((size_t)BATCH * 64 * 4);
  const int Kdim[5] = {64, 1024, 1024, 1024, 1024};
  const int Ndim[5] = {1024, 1024, 1024, 1024, 64};
  unsigned short* Wh[5];
  for (int i = 0; i < 5; ++i)
    Wh[i] = (unsigned short*)alloc((size_t)Ndim[i] * Kdim[i] * 2);

  for (int i = 0; i < 5; ++i) {
    const int total = Ndim[i] * Kdim[i];
    conv_w<<<(total + 255) / 256, 256, 0, stream>>>(W[i], Wh[i], Ndim[i], Kdim[i]);
  }
  init_y<<<BATCH * 64 / 256, 256, 0, stream>>>(x, aug, y, yh);

  const float dt = 0.125f;
  float* outp = (float*)d_out;

  auto eval = [&](float t, int mode, float* op) {
    gemm_h<128, 128, 2, 4, 4, 64, 1024, true>
        <<<dim3(BATCH / 128, 1024 / 128), 256, 0, stream>>>(
            yh, Wh[0], W[0], b[0], t, h1);
    unsigned short* src = h1;
    unsigned short* dst = h2;
    for (int L = 1; L <= 3; ++L) {
      gemm_h<128, 128, 2, 4, 4, 1024, 1024, true>
          <<<dim3(BATCH / 128, 1024 / 128), 256, 0, stream>>>(
              src, Wh[L], W[L], b[L], t, dst);
      unsigned short* tmp = src; src = dst; dst = tmp;
    }
    gemm_l4<<<dim3(BATCH / 32, 1), 256, 0, stream>>>(
        src, Wh[4], W[4], b[4], t, y, ksum, yh, op, mode, dt);
  };

  for (int s = 0; s < 8; ++s) {
    const float t0 = s * dt;
    eval(t0, 0, nullptr);
    eval(t0 + 0.5f * dt, 1, nullptr);
    eval(t0 + 0.5f * dt, 2, nullptr);
    eval(t0 + dt, 3, (s == 7) ? outp : nullptr);
  }
}

// Round 4
// 4854.844 us; speedup vs baseline: 1.2985x; 1.0186x over previous
//
#include <hip/hip_runtime.h>
#include <cstdint>
#include <cstddef>

#define BATCH 16384

typedef float f32x4 __attribute__((ext_vector_type(4)));
typedef _Float16 f16x8 __attribute__((ext_vector_type(8)));

__device__ __forceinline__ unsigned short f2h_bits(float f) {
  _Float16 h = (_Float16)f;
  return __builtin_bit_cast(unsigned short, h);
}

__device__ __forceinline__ void async_cp16(const void* g, void* l) {
  __builtin_amdgcn_global_load_lds(
      (const __attribute__((address_space(1))) unsigned int*)g,
      (__attribute__((address_space(3))) unsigned int*)l, 16, 0, 0);
}

// ---------------------------------------------------------------------------
// Hidden-layer GEMM, double-buffered, FAT WAVE TILES (128x64 per wave).
// C = relu(A[M,K] * Bw[N,K]^T + (bias + t*W[:,K])).
// Block tile 256x128, 4 waves in 2x2, RT=8 x CT=4 MFMAs (16x16x32 f16).
// LDS frag traffic scales as (1/128 + 1/64) vs (1/64 + 1/64): -25% per FLOP.
// BK=32, XOR swizzle cp = c ^ ((row>>1)&3) -> 2-way max (free, m136).
// ---------------------------------------------------------------------------
template <int BM, int BN, int RT, int CT, int K, int N, bool RELU>
__launch_bounds__(256, 2)
__global__ void gemm_h(const unsigned short* __restrict__ A,
                       const unsigned short* __restrict__ Bw,
                       const float* __restrict__ Wfull,
                       const float* __restrict__ bias,
                       float tval,
                       unsigned short* __restrict__ Ch) {
  constexpr int BK = 32;
  constexpr int NI = K / BK;
  __shared__ __align__(16) unsigned short smA[2][BM * BK];
  __shared__ __align__(16) unsigned short smB[2][BN * BK];
  __shared__ float biasLds[BN];

  const int tid = threadIdx.x;
  const int wave = tid >> 6;
  const int lane = tid & 63;
  const int quad = lane >> 4;
  const int r16 = lane & 15;

  const int rowA0 = blockIdx.x * BM;
  const int rowB0 = blockIdx.y * BN;
  const int waveM = wave >> 1;  // 2 wave-rows
  const int waveN = wave & 1;   // 2 wave-cols

  // effective bias = b[col] + t * W[col][K] (time-column fold)
  if (tid < BN) {
    const int col = rowB0 + tid;
    biasLds[tid] = bias[col] + tval * Wfull[(size_t)col * (K + 1) + K];
  }

  auto stage = [&](int k0, int buf) {
#pragma unroll
    for (int i = 0; i < BM * 4 / 256; ++i) {
      const int s = i * 256 + tid;                // LDS 16B-chunk position
      const int row = s >> 2;
      const int c = (s & 3) ^ ((row >> 1) & 3);   // global chunk (swizzled)
      const unsigned short* g = A + (size_t)(rowA0 + row) * K + (k0 + c * 8);
      char* l = ((char*)smA[buf]) + (size_t)(i * 256 + (wave << 6)) * 16;
      async_cp16(g, l);
    }
#pragma unroll
    for (int i = 0; i < BN * 4 / 256; ++i) {
      const int s = i * 256 + tid;
      const int row = s >> 2;
      const int c = (s & 3) ^ ((row >> 1) & 3);
      const unsigned short* g = Bw + (size_t)(rowB0 + row) * K + (k0 + c * 8);
      char* l = ((char*)smB[buf]) + (size_t)(i * 256 + (wave << 6)) * 16;
      async_cp16(g, l);
    }
  };

  f32x4 acc[RT][CT];
  const f32x4 zero = {0.f, 0.f, 0.f, 0.f};
#pragma unroll
  for (int i = 0; i < RT; ++i)
#pragma unroll
    for (int j = 0; j < CT; ++j) acc[i][j] = zero;

  stage(0, 0);  // prefetch iter 0

#pragma unroll 2
  for (int kk = 0; kk < NI; ++kk) {
    __syncthreads();  // drains vmcnt(0): buf[kk&1] ready
    if (kk + 1 < NI) stage((kk + 1) * BK, (kk + 1) & 1);  // prefetch next

    const unsigned short* sA = smA[kk & 1];
    const unsigned short* sB = smB[kk & 1];
    f16x8 af[RT], bfr[CT];
#pragma unroll
    for (int nt = 0; nt < CT; ++nt) {
      const int row = (waveN * CT + nt) * 16 + r16;
      const int cp = quad ^ ((row >> 1) & 3);
      bfr[nt] = *(const f16x8*)(sB + row * BK + cp * 8);
    }
#pragma unroll
    for (int mt = 0; mt < RT; ++mt) {
      const int row = (waveM * RT + mt) * 16 + r16;
      const int cp = quad ^ ((row >> 1) & 3);
      af[mt] = *(const f16x8*)(sA + row * BK + cp * 8);
    }
#pragma unroll
    for (int mt = 0; mt < RT; ++mt)
#pragma unroll
      for (int nt = 0; nt < CT; ++nt)
        acc[mt][nt] =
            __builtin_amdgcn_mfma_f32_16x16x32_f16(af[mt], bfr[nt], acc[mt][nt], 0, 0, 0);
  }

  // epilogue: C/D layout col=lane&15, row=(lane>>4)*4+r
#pragma unroll
  for (int mt = 0; mt < RT; ++mt) {
    const int grow0 = rowA0 + (waveM * RT + mt) * 16 + quad * 4;
#pragma unroll
    for (int nt = 0; nt < CT; ++nt) {
      const int lcol = (waveN * CT + nt) * 16 + r16;
      const int gcol = rowB0 + lcol;
      const float bi = biasLds[lcol];
#pragma unroll
      for (int r = 0; r < 4; ++r) {
        float v = acc[mt][nt][r] + bi;
        if (RELU) v = fmaxf(v, 0.0f);
        Ch[(size_t)(grow0 + r) * N + gcol] = f2h_bits(v);
      }
    }
  }
}

// ---------------------------------------------------------------------------
// Last layer fused with RK4 combine (BM=32, BN=64 full width), dbuf BK=32.
// ---------------------------------------------------------------------------
__launch_bounds__(256, 4)
__global__ void gemm_l4(const unsigned short* __restrict__ A,
                        const unsigned short* __restrict__ Bw,
                        const float* __restrict__ Wfull,
                        const float* __restrict__ bias,
                        float tval,
                        float* __restrict__ y, float* __restrict__ ksum,
                        unsigned short* __restrict__ yh,
                        float* __restrict__ outp, int mode, float dt) {
  constexpr int K = 1024, BK = 32, BM = 32, BN = 64, NI = K / BK;
  __shared__ __align__(16) unsigned short smA[2][BM * BK];
  __shared__ __align__(16) unsigned short smB[2][BN * BK];
  __shared__ float biasLds[BN];

  const int tid = threadIdx.x;
  const int wave = tid >> 6;
  const int lane = tid & 63;
  const int quad = lane >> 4;
  const int r16 = lane & 15;

  const int rowA0 = blockIdx.x * BM;
  const int waveM = wave >> 1;
  const int waveN = wave & 1;

  if (tid < BN) {
    biasLds[tid] = bias[tid] + tval * Wfull[(size_t)tid * (K + 1) + K];
  }

  auto stage = [&](int k0, int buf) {
    if (tid < BM * 4) {  // A: 128 chunks
      const int s = tid;
      const int row = s >> 2;
      const int c = (s & 3) ^ ((row >> 1) & 3);
      const unsigned short* g = A + (size_t)(rowA0 + row) * K + (k0 + c * 8);
      char* l = ((char*)smA[buf]) + (size_t)(wave << 6) * 16;
      async_cp16(g, l);
    }
    {  // B: 256 chunks
      const int s = tid;
      const int row = s >> 2;
      const int c = (s & 3) ^ ((row >> 1) & 3);
      const unsigned short* g = Bw + (size_t)row * K + (k0 + c * 8);
      char* l = ((char*)smB[buf]) + (size_t)(wave << 6) * 16;
      async_cp16(g, l);
    }
  };

  f32x4 acc[2];
  const f32x4 zero = {0.f, 0.f, 0.f, 0.f};
  acc[0] = zero; acc[1] = zero;

  stage(0, 0);

#pragma unroll 2
  for (int kk = 0; kk < NI; ++kk) {
    __syncthreads();
    if (kk + 1 < NI) stage((kk + 1) * BK, (kk + 1) & 1);

    const unsigned short* sA = smA[kk & 1];
    const unsigned short* sB = smB[kk & 1];
    f16x8 af, bfr[2];
    {
      const int row = waveM * 16 + r16;
      const int cp = quad ^ ((row >> 1) & 3);
      af = *(const f16x8*)(sA + row * BK + cp * 8);
    }
#pragma unroll
    for (int nt = 0; nt < 2; ++nt) {
      const int row = (waveN * 2 + nt) * 16 + r16;
      const int cp = quad ^ ((row >> 1) & 3);
      bfr[nt] = *(const f16x8*)(sB + row * BK + cp * 8);
    }
#pragma unroll
    for (int nt = 0; nt < 2; ++nt)
      acc[nt] = __builtin_amdgcn_mfma_f32_16x16x32_f16(af, bfr[nt], acc[nt], 0, 0, 0);
  }

  // epilogue + fused RK4 combine
  const int grow0 = rowA0 + waveM * 16 + quad * 4;
#pragma unroll
  for (int nt = 0; nt < 2; ++nt) {
    const int col = waveN * 32 + nt * 16 + r16;
    const float bi = biasLds[col];
#pragma unroll
    for (int r = 0; r < 4; ++r) {
      const float k = acc[nt][r] + bi;
      const int row = grow0 + r;
      const int idx = row * 64 + col;
      if (mode == 0) {
        ksum[idx] = k;
        yh[idx] = f2h_bits(y[idx] + 0.5f * dt * k);
      } else if (mode == 1) {
        ksum[idx] += 2.f * k;
        yh[idx] = f2h_bits(y[idx] + 0.5f * dt * k);
      } else if (mode == 2) {
        ksum[idx] += 2.f * k;
        yh[idx] = f2h_bits(y[idx] + dt * k);
      } else {
        const float yn = y[idx] + (dt / 6.f) * (ksum[idx] + k);
        y[idx] = yn;
        yh[idx] = f2h_bits(yn);
        if (outp && col < 32) outp[row * 32 + col] = yn;
      }
    }
  }
}

// fp32 W (N x (K+1), time col dropped) -> fp16 Wh (N x K)
__global__ void conv_w(const float* __restrict__ W, unsigned short* __restrict__ Wh,
                       int N, int K) {
  const int idx = blockIdx.x * 256 + threadIdx.x;
  if (idx < N * K) {
    const int n = idx / K;
    const int k = idx - n * K;
    Wh[idx] = f2h_bits(W[(size_t)n * (K + 1) + k]);
  }
}

// y0 = concat(x, aug); also fp16 copy for first GEMM
__global__ void init_y(const float* __restrict__ x, const float* __restrict__ aug,
                       float* __restrict__ y, unsigned short* __restrict__ yh) {
  const int idx = blockIdx.x * 256 + threadIdx.x;  // BATCH*64
  const int i = idx >> 6;
  const int j = idx & 63;
  const float v = (j < 32) ? x[i * 32 + j] : aug[i * 32 + (j - 32)];
  y[idx] = v;
  yh[idx] = f2h_bits(v);
}

extern "C" void kernel_launch(void* const* d_in, const int* in_sizes, int n_in,
                              void* d_out, int out_size, void* d_ws, size_t ws_size,
                              hipStream_t stream) {
  const float* x = (const float*)d_in[0];
  const float* aug = (const float*)d_in[1];
  const float* W[5];
  const float* b[5];
  for (int i = 0; i < 5; ++i) {
    W[i] = (const float*)d_in[2 + 2 * i];
    b[i] = (const float*)d_in[3 + 2 * i];
  }

  char* ws = (char*)d_ws;
  auto alloc = [&](size_t bytes) -> char* {
    char* p = ws;
    ws += (bytes + 255) & ~(size_t)255;
    return p;
  };
  float* y = (float*)alloc((size_t)BATCH * 64 * 4);
  unsigned short* yh = (unsigned short*)alloc((size_t)BATCH * 64 * 2);
  unsigned short* h1 = (unsigned short*)alloc((size_t)BATCH * 1024 * 2);
  unsigned short* h2 = (unsigned short*)alloc((size_t)BATCH * 1024 * 2);
  float* ksum = (float*)alloc((size_t)BATCH * 64 * 4);
  const int Kdim[5] = {64, 1024, 1024, 1024, 1024};
  const int Ndim[5] = {1024, 1024, 1024, 1024, 64};
  unsigned short* Wh[5];
  for (int i = 0; i < 5; ++i)
    Wh[i] = (unsigned short*)alloc((size_t)Ndim[i] * Kdim[i] * 2);

  for (int i = 0; i < 5; ++i) {
    const int total = Ndim[i] * Kdim[i];
    conv_w<<<(total + 255) / 256, 256, 0, stream>>>(W[i], Wh[i], Ndim[i], Kdim[i]);
  }
  init_y<<<BATCH * 64 / 256, 256, 0, stream>>>(x, aug, y, yh);

  const float dt = 0.125f;
  float* outp = (float*)d_out;

  auto eval = [&](float t, int mode, float* op) {
    // layer 0: [B,64] x [64,1024]^T -> h1
    gemm_h<256, 128, 8, 4, 64, 1024, true>
        <<<dim3(BATCH / 256, 1024 / 128), 256, 0, stream>>>(
            yh, Wh[0], W[0], b[0], t, h1);
    unsigned short* src = h1;
    unsigned short* dst = h2;
    for (int L = 1; L <= 3; ++L) {
      gemm_h<256, 128, 8, 4, 1024, 1024, true>
          <<<dim3(BATCH / 256, 1024 / 128), 256, 0, stream>>>(
              src, Wh[L], W[L], b[L], t, dst);
      unsigned short* tmp = src; src = dst; dst = tmp;
    }
    gemm_l4<<<dim3(BATCH / 32, 1), 256, 0, stream>>>(
        src, Wh[4], W[4], b[4], t, y, ksum, yh, op, mode, dt);
  };

  for (int s = 0; s < 8; ++s) {
    const float t0 = s * dt;
    eval(t0, 0, nullptr);
    eval(t0 + 0.5f * dt, 1, nullptr);
    eval(t0 + 0.5f * dt, 2, nullptr);
    eval(t0 + dt, 3, (s == 7) ? outp : nullptr);
  }
}